// Round 1
// baseline (991.534 us; speedup 1.0000x reference)
//
#include <hip/hip_runtime.h>
#include <hip/hip_bf16.h>
#include <cstdint>
#include <cstddef>

// ---------------- types ----------------
typedef __bf16 bf16x8 __attribute__((ext_vector_type(8)));
typedef __bf16 bf16x4 __attribute__((ext_vector_type(4)));
typedef float  f32x4  __attribute__((ext_vector_type(4)));

#define D_MODEL 2048
#define SEQ     4096
#define BATCH   4
#define M_TOK   (BATCH * SEQ)            // 16384 tokens
#define ATTN_SCALE 0.08838834764831845f  // 128^-0.5

#define BM 128
#define BN 128
#define BK 32

#define NSEG   64
#define SEGLEN (SEQ / NSEG)              // 64

// ---------------- helpers ----------------
__device__ __forceinline__ void async_load16(const void* g, void* l) {
    __builtin_amdgcn_global_load_lds(
        (const __attribute__((address_space(1))) unsigned int*)g,
        (__attribute__((address_space(3))) unsigned int*)l,
        16, 0, 0);
}

// ---------------- cast fp32 -> bf16 (8 elems / thread) ----------------
__global__ __launch_bounds__(256) void k_cast_bf16(const float* __restrict__ in,
                                                   __bf16* __restrict__ out,
                                                   int n8) {
    int i = blockIdx.x * 256 + threadIdx.x;
    if (i >= n8) return;
    const float4* in4 = (const float4*)in;
    float4 a = in4[2 * i];
    float4 b = in4[2 * i + 1];
    bf16x8 o;
    o[0] = (__bf16)a.x; o[1] = (__bf16)a.y; o[2] = (__bf16)a.z; o[3] = (__bf16)a.w;
    o[4] = (__bf16)b.x; o[5] = (__bf16)b.y; o[6] = (__bf16)b.z; o[7] = (__bf16)b.w;
    ((bf16x8*)out)[i] = o;
}

// ---------------- GEMM: C = A (M x K, row-major) * B^T (B is N x K row-major) ----------------
// Block: 256 threads = 4 waves in 2x2; wave tile 64x64; MFMA 16x16x32 bf16.
// PHI: apply elu+1 in epilogue. OUT_T: __bf16 or float.
template <int PHI, typename OUT_T>
__device__ __forceinline__ void gemm_bt(const __bf16* __restrict__ A,
                                        const __bf16* __restrict__ Bm,
                                        const float* __restrict__ bias,
                                        OUT_T* __restrict__ C,
                                        int K, int N) {
    __shared__ __align__(16) __bf16 As[BM * BK];
    __shared__ __align__(16) __bf16 Bs[BN * BK];

    const int tid  = threadIdx.x;
    const int lane = tid & 63;
    const int wave = tid >> 6;
    const int waveM = wave & 1;
    const int waveN = wave >> 1;
    const long bm = (long)blockIdx.y * BM;
    const long bn = (long)blockIdx.x * BN;

    // staging: each thread loads 16B (8 bf16) per instruction; 4 lanes per 32-elem row
    const __bf16* ga0 = A  + (bm + (tid >> 2)) * (long)K + (tid & 3) * 8;
    const __bf16* ga1 = ga0 + 64L * K;
    const __bf16* gb0 = Bm + (bn + (tid >> 2)) * (long)K + (tid & 3) * 8;
    const __bf16* gb1 = gb0 + 64L * K;
    __bf16* la0 = As + tid * 8;
    __bf16* la1 = As + 2048 + tid * 8;
    __bf16* lb0 = Bs + tid * 8;
    __bf16* lb1 = Bs + 2048 + tid * 8;

    // fragment read offsets (A-layout: m = lane&15, k = (lane>>4)*8 + j)
    const int mrow = waveM * 64 + (lane & 15);
    const int nrow = waveN * 64 + (lane & 15);
    const int kq   = (lane >> 4) * 8;

    f32x4 acc[4][4] = {};

    for (int k0 = 0; k0 < K; k0 += BK) {
        async_load16(ga0 + k0, la0);
        async_load16(ga1 + k0, la1);
        async_load16(gb0 + k0, lb0);
        async_load16(gb1 + k0, lb1);
        __syncthreads();

        bf16x8 af[4], bfr[4];
#pragma unroll
        for (int i = 0; i < 4; i++)
            af[i] = *(const bf16x8*)(As + (mrow + i * 16) * BK + kq);
#pragma unroll
        for (int j = 0; j < 4; j++)
            bfr[j] = *(const bf16x8*)(Bs + (nrow + j * 16) * BK + kq);
#pragma unroll
        for (int i = 0; i < 4; i++)
#pragma unroll
            for (int j = 0; j < 4; j++)
                acc[i][j] = __builtin_amdgcn_mfma_f32_16x16x32_bf16(
                    af[i], bfr[j], acc[i][j], 0, 0, 0);
        __syncthreads();
    }

    // epilogue: D elem (row = (lane>>4)*4 + r  [M index], col = lane&15 [N index])
    const int r0 = (lane >> 4) * 4;
    const int cn = lane & 15;
#pragma unroll
    for (int i = 0; i < 4; i++) {
        long mg = bm + waveM * 64 + i * 16 + r0;
#pragma unroll
        for (int j = 0; j < 4; j++) {
            long ng = bn + waveN * 64 + j * 16 + cn;
            float bia = bias[ng];
#pragma unroll
            for (int r = 0; r < 4; r++) {
                float v = acc[i][j][r] + bia;
                if (PHI) v = (v > 0.f) ? (v + 1.f) : __expf(v);
                C[(mg + r) * (long)N + ng] = (OUT_T)v;
            }
        }
    }
}

__global__ __launch_bounds__(256) void k_gemm_qkv(
    const __bf16* __restrict__ xb,
    const __bf16* __restrict__ wq, const __bf16* __restrict__ wk, const __bf16* __restrict__ wv,
    const float* __restrict__ bq, const float* __restrict__ bk, const float* __restrict__ bv,
    __bf16* __restrict__ oq, __bf16* __restrict__ ok, __bf16* __restrict__ ov) {
    const int z = blockIdx.z;
    const __bf16* W = (z == 0) ? wq : (z == 1) ? wk : wv;
    const float*  b = (z == 0) ? bq : (z == 1) ? bk : bv;
    __bf16*       o = (z == 0) ? oq : (z == 1) ? ok : ov;
    if (z < 2)
        gemm_bt<1, __bf16>(xb, W, b, o, D_MODEL, D_MODEL);   // phi(q), phi(k)
    else
        gemm_bt<0, __bf16>(xb, W, b, o, D_MODEL, D_MODEL);   // v
}

__global__ __launch_bounds__(256) void k_gemm_out(
    const __bf16* __restrict__ ctx, const __bf16* __restrict__ wo,
    const float* __restrict__ bo, float* __restrict__ out) {
    gemm_bt<0, float>(ctx, wo, bo, out, D_MODEL, D_MODEL);
}

// ---------------- scan pass 1: per-segment sums of phi_k * v ----------------
// grid (2, NSEG, B); 256 threads; each thread owns 4 channels.
__global__ __launch_bounds__(256) void k_scan_partial(
    const __bf16* __restrict__ phik, const __bf16* __restrict__ v,
    float* __restrict__ partial) {
    const int b  = blockIdx.z;
    const int s  = blockIdx.y;
    const int c0 = blockIdx.x * 1024 + threadIdx.x * 4;
    long base = ((long)b * SEQ + (long)s * SEGLEN) * D_MODEL + c0;
    const bf16x4* pk = (const bf16x4*)(phik + base);
    const bf16x4* pv = (const bf16x4*)(v + base);
    float s0 = 0, s1 = 0, s2 = 0, s3 = 0;
    for (int l = 0; l < SEGLEN; l++) {
        bf16x4 a = *pk, w = *pv;
        s0 += (float)a[0] * (float)w[0];
        s1 += (float)a[1] * (float)w[1];
        s2 += (float)a[2] * (float)w[2];
        s3 += (float)a[3] * (float)w[3];
        pk += D_MODEL / 4; pv += D_MODEL / 4;
    }
    *(float4*)(partial + ((long)(b * NSEG + s)) * D_MODEL + c0) = make_float4(s0, s1, s2, s3);
}

// ---------------- scan pass 2: running sum + context write (in-place over phik) ----------------
__global__ __launch_bounds__(256) void k_scan_apply(
    const __bf16* __restrict__ phiq,
    __bf16* phik_ctx,                    // read phik, write ctx in-place (aliased)
    const __bf16* __restrict__ v,
    const float* __restrict__ partial) {
    const int b  = blockIdx.z;
    const int s  = blockIdx.y;
    const int c0 = blockIdx.x * 1024 + threadIdx.x * 4;
    float r0 = 0, r1 = 0, r2 = 0, r3 = 0;
    for (int sp = 0; sp < s; sp++) {
        float4 p = *(const float4*)(partial + ((long)(b * NSEG + sp)) * D_MODEL + c0);
        r0 += p.x; r1 += p.y; r2 += p.z; r3 += p.w;
    }
    long base = ((long)b * SEQ + (long)s * SEGLEN) * D_MODEL + c0;
    bf16x4* pk = (bf16x4*)(phik_ctx + base);
    const bf16x4* pv = (const bf16x4*)(v + base);
    const bf16x4* pq = (const bf16x4*)(phiq + base);
    for (int l = 0; l < SEGLEN; l++) {
        bf16x4 a = *pk, w = *pv, q = *pq;
        r0 += (float)a[0] * (float)w[0];
        r1 += (float)a[1] * (float)w[1];
        r2 += (float)a[2] * (float)w[2];
        r3 += (float)a[3] * (float)w[3];
        bf16x4 o;
        o[0] = (__bf16)((float)q[0] * r0 * ATTN_SCALE);
        o[1] = (__bf16)((float)q[1] * r1 * ATTN_SCALE);
        o[2] = (__bf16)((float)q[2] * r2 * ATTN_SCALE);
        o[3] = (__bf16)((float)q[3] * r3 * ATTN_SCALE);
        *pk = o;
        pk += D_MODEL / 4; pv += D_MODEL / 4; pq += D_MODEL / 4;
    }
}

// ---------------- launch ----------------
extern "C" void kernel_launch(void* const* d_in, const int* in_sizes, int n_in,
                              void* d_out, int out_size, void* d_ws, size_t ws_size,
                              hipStream_t stream) {
    const float* x  = (const float*)d_in[0];
    const float* Wq = (const float*)d_in[1];
    const float* bq = (const float*)d_in[2];
    const float* Wk = (const float*)d_in[3];
    const float* bk = (const float*)d_in[4];
    const float* Wv = (const float*)d_in[5];
    const float* bv = (const float*)d_in[6];
    const float* Wo = (const float*)d_in[7];
    const float* bo = (const float*)d_in[8];

    const size_t XB = (size_t)M_TOK * D_MODEL;   // 33,554,432 elems
    const size_t WB = (size_t)D_MODEL * D_MODEL; //  4,194,304 elems

    char* p = (char*)d_ws;
    __bf16* xb   = (__bf16*)p; p += XB * 2;
    __bf16* wqb  = (__bf16*)p; p += WB * 2;
    __bf16* wkb  = (__bf16*)p; p += WB * 2;
    __bf16* wvb  = (__bf16*)p; p += WB * 2;
    __bf16* wob  = (__bf16*)p; p += WB * 2;
    __bf16* phiq = (__bf16*)p; p += XB * 2;
    __bf16* phik = (__bf16*)p; p += XB * 2;
    __bf16* vb   = (__bf16*)p; p += XB * 2;
    if ((size_t)(p - (char*)d_ws) > ws_size) return;  // workspace too small: bail

    float*  partial = (float*)xb;  // xb is dead after the QKV GEMMs; reuse for 2 MB partials
    __bf16* ctx     = phik;        // context written in-place over phi_k

    // 1) casts
    k_cast_bf16<<<dim3((unsigned)(XB / 8 / 256)), 256, 0, stream>>>(x, xb, (int)(XB / 8));
    k_cast_bf16<<<dim3((unsigned)(WB / 8 / 256)), 256, 0, stream>>>(Wq, wqb, (int)(WB / 8));
    k_cast_bf16<<<dim3((unsigned)(WB / 8 / 256)), 256, 0, stream>>>(Wk, wkb, (int)(WB / 8));
    k_cast_bf16<<<dim3((unsigned)(WB / 8 / 256)), 256, 0, stream>>>(Wv, wvb, (int)(WB / 8));
    k_cast_bf16<<<dim3((unsigned)(WB / 8 / 256)), 256, 0, stream>>>(Wo, wob, (int)(WB / 8));

    // 2) fused QKV projection (+phi on q,k)
    k_gemm_qkv<<<dim3(D_MODEL / BN, M_TOK / BM, 3), 256, 0, stream>>>(
        xb, wqb, wkb, wvb, bq, bk, bv, phiq, phik, vb);

    // 3) segmented prefix sum of phi_k * v, then context = phi_q * cumsum * scale
    k_scan_partial<<<dim3(2, NSEG, BATCH), 256, 0, stream>>>(phik, vb, partial);
    k_scan_apply<<<dim3(2, NSEG, BATCH), 256, 0, stream>>>(phiq, phik, vb, partial);

    // 4) output projection -> fp32 d_out
    k_gemm_out<<<dim3(D_MODEL / BN, M_TOK / BM, 1), 256, 0, stream>>>(
        ctx, wob, bo, (float*)d_out);
}

// Round 2
// 928.885 us; speedup vs baseline: 1.0674x; 1.0674x over previous
//
#include <hip/hip_runtime.h>
#include <hip/hip_bf16.h>
#include <cstdint>
#include <cstddef>

// ---------------- types ----------------
typedef __bf16 bf16x8 __attribute__((ext_vector_type(8)));
typedef __bf16 bf16x4 __attribute__((ext_vector_type(4)));
typedef float  f32x4  __attribute__((ext_vector_type(4)));

#define D_MODEL 2048
#define SEQ     4096
#define BATCH   4
#define M_TOK   (BATCH * SEQ)            // 16384 tokens
#define ATTN_SCALE 0.08838834764831845f  // 128^-0.5

#define BM 128
#define BN 128
#define BK 64                            // 128B rows -> 8x16B chunks, XOR swizzle

#define NSEG   64
#define SEGLEN (SEQ / NSEG)              // 64

// ---------------- helpers ----------------
__device__ __forceinline__ void async_load16(const void* g, void* l) {
    __builtin_amdgcn_global_load_lds(
        (const __attribute__((address_space(1))) unsigned int*)g,
        (__attribute__((address_space(3))) unsigned int*)l,
        16, 0, 0);
}

// ---------------- cast fp32 -> bf16 (8 elems / thread) ----------------
__global__ __launch_bounds__(256) void k_cast_bf16(const float* __restrict__ in,
                                                   __bf16* __restrict__ out,
                                                   int n8) {
    int i = blockIdx.x * 256 + threadIdx.x;
    if (i >= n8) return;
    const float4* in4 = (const float4*)in;
    float4 a = in4[2 * i];
    float4 b = in4[2 * i + 1];
    bf16x8 o;
    o[0] = (__bf16)a.x; o[1] = (__bf16)a.y; o[2] = (__bf16)a.z; o[3] = (__bf16)a.w;
    o[4] = (__bf16)b.x; o[5] = (__bf16)b.y; o[6] = (__bf16)b.z; o[7] = (__bf16)b.w;
    ((bf16x8*)out)[i] = o;
}

// 4 weight matrices in one launch: blockIdx.y picks which
__global__ __launch_bounds__(256) void k_cast_w4(const float* __restrict__ w0,
                                                 const float* __restrict__ w1,
                                                 const float* __restrict__ w2,
                                                 const float* __restrict__ w3,
                                                 __bf16* __restrict__ out, int n8) {
    const float* srcs[4] = {w0, w1, w2, w3};
    const float* in = srcs[blockIdx.y];
    __bf16* o = out + (size_t)blockIdx.y * (size_t)n8 * 8;
    int i = blockIdx.x * 256 + threadIdx.x;
    if (i >= n8) return;
    const float4* in4 = (const float4*)in;
    float4 a = in4[2 * i];
    float4 b = in4[2 * i + 1];
    bf16x8 v;
    v[0] = (__bf16)a.x; v[1] = (__bf16)a.y; v[2] = (__bf16)a.z; v[3] = (__bf16)a.w;
    v[4] = (__bf16)b.x; v[5] = (__bf16)b.y; v[6] = (__bf16)b.z; v[7] = (__bf16)b.w;
    ((bf16x8*)o)[i] = v;
}

// ---------------- GEMM: C = A (M x K, row-major) * B^T (B is N x K row-major) ----------------
// 256 threads = 4 waves (2x2 of 64x64 wave tiles), MFMA 16x16x32 bf16, BK=64.
// LDS layout: element (row r, 16B-chunk c) lives at byte r*128 + (c ^ (r&7))*16.
// Swizzle applied on the GLOBAL side of global_load_lds (LDS dest stays lane-contiguous).
template <int PHI, typename OUT_T>
__device__ __forceinline__ void gemm_bt(const __bf16* __restrict__ A,
                                        const __bf16* __restrict__ Bm,
                                        const float* __restrict__ bias,
                                        OUT_T* __restrict__ C,
                                        int K, int N) {
    __shared__ __align__(16) __bf16 As[BM * BK];   // 16 KB
    __shared__ __align__(16) __bf16 Bs[BN * BK];   // 16 KB

    const int tid  = threadIdx.x;
    const int lane = tid & 63;
    const int wave = tid >> 6;
    const int waveM = wave & 1;
    const int waveN = wave >> 1;
    const long bm = (long)blockIdx.y * BM;
    const long bn = (long)blockIdx.x * BN;

    // staging: 4 async_load16 per matrix; instr q covers rows [q*32, q*32+32)
    // thread t: row = q*32 + (t>>3), physical chunk p = t&7 holds logical chunk p^(r&7)
    const int srow  = tid >> 3;          // 0..31
    const int sphys = tid & 7;           // 0..7
    const __bf16* gA[4]; const __bf16* gB[4];
    __bf16* lA[4]; __bf16* lB[4];
#pragma unroll
    for (int q = 0; q < 4; q++) {
        int r  = q * 32 + srow;
        int cb = (sphys ^ (r & 7)) * 8;  // logical k-offset (elems) this lane fetches
        gA[q] = A  + (bm + r) * (long)K + cb;
        gB[q] = Bm + (bn + r) * (long)K + cb;
        lA[q] = As + q * 2048 + tid * 8;
        lB[q] = Bs + q * 2048 + tid * 8;
    }

    const int mrow = waveM * 64 + (lane & 15);
    const int nrow = waveN * 64 + (lane & 15);
    const int ksel = lane >> 4;          // 0..3 (8-elem chunk within 32-wide k window)

    f32x4 acc[4][4] = {};

    for (int k0 = 0; k0 < K; k0 += BK) {
#pragma unroll
        for (int q = 0; q < 4; q++) async_load16(gA[q] + k0, lA[q]);
#pragma unroll
        for (int q = 0; q < 4; q++) async_load16(gB[q] + k0, lB[q]);
        __syncthreads();

#pragma unroll
        for (int s = 0; s < 2; s++) {    // two 32-wide k sub-tiles
            bf16x8 af[4], bfr[4];
#pragma unroll
            for (int i = 0; i < 4; i++) {
                int r = mrow + i * 16;
                int p = (s * 4 + ksel) ^ (r & 7);
                af[i] = *(const bf16x8*)(As + r * 64 + p * 8);
            }
#pragma unroll
            for (int j = 0; j < 4; j++) {
                int r = nrow + j * 16;
                int p = (s * 4 + ksel) ^ (r & 7);
                bfr[j] = *(const bf16x8*)(Bs + r * 64 + p * 8);
            }
#pragma unroll
            for (int i = 0; i < 4; i++)
#pragma unroll
                for (int j = 0; j < 4; j++)
                    acc[i][j] = __builtin_amdgcn_mfma_f32_16x16x32_bf16(
                        af[i], bfr[j], acc[i][j], 0, 0, 0);
        }
        __syncthreads();
    }

    // epilogue: D elem (row = (lane>>4)*4 + r [M], col = lane&15 [N])
    const int r0 = (lane >> 4) * 4;
    const int cn = lane & 15;
#pragma unroll
    for (int i = 0; i < 4; i++) {
        long mg = bm + waveM * 64 + i * 16 + r0;
#pragma unroll
        for (int j = 0; j < 4; j++) {
            long ng = bn + waveN * 64 + j * 16 + cn;
            float bia = bias[ng];
#pragma unroll
            for (int r = 0; r < 4; r++) {
                float v = acc[i][j][r] + bia;
                if (PHI) v = (v > 0.f) ? (v + 1.f) : __expf(v);
                C[(mg + r) * (long)N + ng] = (OUT_T)v;
            }
        }
    }
}

__global__ __launch_bounds__(256) void k_gemm_qkv(
    const __bf16* __restrict__ xb,
    const __bf16* __restrict__ wq, const __bf16* __restrict__ wk, const __bf16* __restrict__ wv,
    const float* __restrict__ bq, const float* __restrict__ bk, const float* __restrict__ bv,
    __bf16* __restrict__ oq, __bf16* __restrict__ ok, __bf16* __restrict__ ov) {
    const int z = blockIdx.z;
    const __bf16* W = (z == 0) ? wq : (z == 1) ? wk : wv;
    const float*  b = (z == 0) ? bq : (z == 1) ? bk : bv;
    __bf16*       o = (z == 0) ? oq : (z == 1) ? ok : ov;
    if (z < 2)
        gemm_bt<1, __bf16>(xb, W, b, o, D_MODEL, D_MODEL);   // phi(q), phi(k)
    else
        gemm_bt<0, __bf16>(xb, W, b, o, D_MODEL, D_MODEL);   // v
}

__global__ __launch_bounds__(256) void k_gemm_out(
    const __bf16* __restrict__ ctx, const __bf16* __restrict__ wo,
    const float* __restrict__ bo, float* __restrict__ out) {
    gemm_bt<0, float>(ctx, wo, bo, out, D_MODEL, D_MODEL);
}

// ---------------- scan pass 1: per-segment sums of phi_k * v ----------------
__global__ __launch_bounds__(256) void k_scan_partial(
    const __bf16* __restrict__ phik, const __bf16* __restrict__ v,
    float* __restrict__ partial) {
    const int b  = blockIdx.z;
    const int s  = blockIdx.y;
    const int c0 = blockIdx.x * 1024 + threadIdx.x * 4;
    long base = ((long)b * SEQ + (long)s * SEGLEN) * D_MODEL + c0;
    const bf16x4* pk = (const bf16x4*)(phik + base);
    const bf16x4* pv = (const bf16x4*)(v + base);
    float s0 = 0, s1 = 0, s2 = 0, s3 = 0;
    for (int l = 0; l < SEGLEN; l++) {
        bf16x4 a = *pk, w = *pv;
        s0 += (float)a[0] * (float)w[0];
        s1 += (float)a[1] * (float)w[1];
        s2 += (float)a[2] * (float)w[2];
        s3 += (float)a[3] * (float)w[3];
        pk += D_MODEL / 4; pv += D_MODEL / 4;
    }
    *(float4*)(partial + ((long)(b * NSEG + s)) * D_MODEL + c0) = make_float4(s0, s1, s2, s3);
}

// ---------------- scan pass 2: running sum + context write (in-place over phik) ----------------
__global__ __launch_bounds__(256) void k_scan_apply(
    const __bf16* __restrict__ phiq,
    __bf16* phik_ctx,
    const __bf16* __restrict__ v,
    const float* __restrict__ partial) {
    const int b  = blockIdx.z;
    const int s  = blockIdx.y;
    const int c0 = blockIdx.x * 1024 + threadIdx.x * 4;
    float r0 = 0, r1 = 0, r2 = 0, r3 = 0;
    for (int sp = 0; sp < s; sp++) {
        float4 p = *(const float4*)(partial + ((long)(b * NSEG + sp)) * D_MODEL + c0);
        r0 += p.x; r1 += p.y; r2 += p.z; r3 += p.w;
    }
    long base = ((long)b * SEQ + (long)s * SEGLEN) * D_MODEL + c0;
    bf16x4* pk = (bf16x4*)(phik_ctx + base);
    const bf16x4* pv = (const bf16x4*)(v + base);
    const bf16x4* pq = (const bf16x4*)(phiq + base);
    for (int l = 0; l < SEGLEN; l++) {
        bf16x4 a = *pk, w = *pv, q = *pq;
        r0 += (float)a[0] * (float)w[0];
        r1 += (float)a[1] * (float)w[1];
        r2 += (float)a[2] * (float)w[2];
        r3 += (float)a[3] * (float)w[3];
        bf16x4 o;
        o[0] = (__bf16)((float)q[0] * r0 * ATTN_SCALE);
        o[1] = (__bf16)((float)q[1] * r1 * ATTN_SCALE);
        o[2] = (__bf16)((float)q[2] * r2 * ATTN_SCALE);
        o[3] = (__bf16)((float)q[3] * r3 * ATTN_SCALE);
        *pk = o;
        pk += D_MODEL / 4; pv += D_MODEL / 4; pq += D_MODEL / 4;
    }
}

// ---------------- launch ----------------
extern "C" void kernel_launch(void* const* d_in, const int* in_sizes, int n_in,
                              void* d_out, int out_size, void* d_ws, size_t ws_size,
                              hipStream_t stream) {
    const float* x  = (const float*)d_in[0];
    const float* Wq = (const float*)d_in[1];
    const float* bq = (const float*)d_in[2];
    const float* Wk = (const float*)d_in[3];
    const float* bk = (const float*)d_in[4];
    const float* Wv = (const float*)d_in[5];
    const float* bv = (const float*)d_in[6];
    const float* Wo = (const float*)d_in[7];
    const float* bo = (const float*)d_in[8];

    const size_t XB = (size_t)M_TOK * D_MODEL;
    const size_t WB = (size_t)D_MODEL * D_MODEL;

    char* p = (char*)d_ws;
    __bf16* xb   = (__bf16*)p; p += XB * 2;
    __bf16* wqb  = (__bf16*)p; p += WB * 2;   // wq,wk,wv,wo contiguous
    __bf16* wkb  = (__bf16*)p; p += WB * 2;
    __bf16* wvb  = (__bf16*)p; p += WB * 2;
    __bf16* wob  = (__bf16*)p; p += WB * 2;
    __bf16* phiq = (__bf16*)p; p += XB * 2;
    __bf16* phik = (__bf16*)p; p += XB * 2;
    __bf16* vb   = (__bf16*)p; p += XB * 2;
    if ((size_t)(p - (char*)d_ws) > ws_size) return;

    float*  partial = (float*)xb;  // xb dead after QKV GEMMs
    __bf16* ctx     = phik;        // context in-place over phi_k

    // 1) casts
    k_cast_bf16<<<dim3((unsigned)(XB / 8 / 256)), 256, 0, stream>>>(x, xb, (int)(XB / 8));
    k_cast_w4<<<dim3((unsigned)(WB / 8 / 256), 4), 256, 0, stream>>>(Wq, Wk, Wv, Wo, wqb, (int)(WB / 8));

    // 2) fused QKV projection (+phi on q,k)
    k_gemm_qkv<<<dim3(D_MODEL / BN, M_TOK / BM, 3), 256, 0, stream>>>(
        xb, wqb, wkb, wvb, bq, bk, bv, phiq, phik, vb);

    // 3) segmented prefix sum of phi_k * v, then context = phi_q * cumsum * scale
    k_scan_partial<<<dim3(2, NSEG, BATCH), 256, 0, stream>>>(phik, vb, partial);
    k_scan_apply<<<dim3(2, NSEG, BATCH), 256, 0, stream>>>(phiq, phik, vb, partial);

    // 4) output projection -> fp32 d_out
    k_gemm_out<<<dim3(D_MODEL / BN, M_TOK / BM, 1), 256, 0, stream>>>(
        ctx, wob, bo, (float*)d_out);
}